// Round 11
// baseline (74.831 us; speedup 1.0000x reference)
//
#include <hip/hip_runtime.h>

#define C_IN     7
#define D_MODEL  512
#define TAO      3
#define M_TAPS   5
#define KERNELS  73            // D_MODEL / C_IN
#define B_SZ     32
#define L_SZ     4096
#define TB       64            // t-positions per block
#define NTB      (L_SZ / TB)   // 64
#define ROWS     (TB + 17)     // 81 staged rows
#define SHIFT    3             // xs row r stored at index r+3 -> fills 16B-aligned
#define RPAD     88
#define CHUNK    4             // rows per chunk: fill = one ds_read_b128
#define NCH      (TB / CHUNK)  // 16

__global__ __launch_bounds__(512, 8) void trc_conv_kernel(
    const float* __restrict__ x,          // [B, L, C_IN]
    const float* __restrict__ conv_w,     // [73, 6, 3]
    const float* __restrict__ conv_b,     // [73]
    const float* __restrict__ leftout_w,  // [1, 6, 3]
    const float* __restrict__ leftout_b,  // [1]
    float* __restrict__ out)              // [B, L, 512]
{
    __shared__ float xs[C_IN][RPAD];
    __shared__ __align__(16) float buf[8][2][CHUNK][64];  // wave-private dbuf out-tiles (16 KB)

    const int tid = threadIdx.x;
    const int wv  = tid >> 6;
    const int ln  = tid & 63;
    const int b   = blockIdx.x / NTB;
    const int tb  = blockIdx.x % NTB;
    const int t0  = tb * TB;

    // Stage x rows [t0-16, t0+TB] (circular), transposed, shifted by +3.
    const float* xb = x + (size_t)b * L_SZ * C_IN;
    for (int i = tid; i < ROWS * C_IN; i += 512) {
        int r = i / C_IN, c = i - r * C_IN;
        int g = t0 - 16 + r;
        if (g < 0)      g += L_SZ;
        if (g >= L_SZ)  g -= L_SZ;
        xs[c][r + SHIFT] = xb[(size_t)g * C_IN + c];
    }
    __syncthreads();   // only barrier

    // Column ownership: d = tid.
    const int d = tid;
    int ch;
    const float* wsrc;
    float bias;
    if (d < C_IN * KERNELS) {
        ch = d / KERNELS;
        int o = d - ch * KERNELS;
        wsrc = conv_w + o * 18;
        bias = conv_b[o];
    } else {
        ch = C_IN - 1;
        wsrc = leftout_w;
        bias = leftout_b[0];
    }
    const float* __restrict__ rowp = &xs[ch][SHIFT];   // rowp[r] = x row t0-16+r

    // FIR weights by row-offset j: k=j%3, m=(15+k-j)/3.
    float wreg[18];
    #pragma unroll
    for (int j = 0; j < 18; ++j) {
        int k = j % 3;
        int m = (15 + k - j) / 3;
        wreg[j] = wsrc[m * 3 + k];
    }

    if (tb == 0 || tb == NTB - 1) {
        // Edge blocks (2/64): masked path (wrap + validity), scalar stores.
        float* outp = out + ((size_t)b * L_SZ + t0) * D_MODEL + d;
        for (int tl = 0; tl < TB; ++tl) {
            float acc = bias;
            #pragma unroll
            for (int k = 0; k < 3; ++k) {
                int tt = t0 + tl + k - 1;
                if (tt < 0)      tt += L_SZ;
                if (tt >= L_SZ)  tt -= L_SZ;
                if (tt >= M_TAPS * TAO) {
                    int lt = tl + 15 + k;
                    #pragma unroll
                    for (int m = 0; m < 6; ++m)
                        acc = fmaf(rowp[lt - 3 * m], wreg[15 + k - 3 * m], acc);
                }
            }
            outp[(size_t)tl * D_MODEL] = acc;
        }
        return;
    }

    // Interior: sliding win[21], chunk=4; per chunk: 1 b128 fill, 16x... 72 FMA,
    // 4 b32 tile writes, 1 b128 readback (this chunk), 1 dwordx4 store (prev).
    float* __restrict__ bufw = &buf[wv][0][0][0];
    float4* o4 = (float4*)(out + ((size_t)b * L_SZ + t0) * D_MODEL + wv * 64);
    const int lr = ln >> 4, lc = ln & 15;    // store lane mapping: row lr, col4 lc

    float win[21];
    #pragma unroll
    for (int q = 0; q < 17; ++q) win[q] = rowp[q];

    float4 r0;

    #pragma unroll
    for (int c = 0; c < NCH; ++c) {
        float* __restrict__ bc = bufw + (c & 1) * (CHUNK * 64);

        // Fill: rows 4c+17..4c+20, idx (17+4c+3)=20+4c -> 16B aligned.
        float4 f = *(const float4*)&rowp[17 + 4 * c];
        win[17] = f.x; win[18] = f.y; win[19] = f.z; win[20] = f.w;

        #pragma unroll
        for (int i = 0; i < CHUNK; ++i) {
            float acc = bias;
            #pragma unroll
            for (int j = 0; j < 18; ++j)
                acc = fmaf(win[i + j], wreg[j], acc);
            bc[i * 64 + ln] = acc;            // stride-1: conflict-free
        }
        #pragma unroll
        for (int q = 0; q < 17; ++q) win[q] = win[q + 4];

        // Readback this chunk (wave-private, in-order DS => no barrier).
        float4 n0 = ((const float4*)bc)[ln];
        __builtin_amdgcn_sched_barrier(0);

        if (c > 0) {
            // store prev chunk: row (c-1)*4+lr, col4 = 16*wv.. handled by o4 base
            o4[(size_t)((c - 1) * CHUNK + lr) * (D_MODEL / 4) + lc] = r0;
        }
        r0 = n0;
    }
    o4[(size_t)((NCH - 1) * CHUNK + lr) * (D_MODEL / 4) + lc] = r0;
}

extern "C" void kernel_launch(void* const* d_in, const int* in_sizes, int n_in,
                              void* d_out, int out_size, void* d_ws, size_t ws_size,
                              hipStream_t stream) {
    const float* x          = (const float*)d_in[0];
    const float* conv_w     = (const float*)d_in[1];
    const float* conv_b     = (const float*)d_in[2];
    const float* leftout_w  = (const float*)d_in[3];
    const float* leftout_b  = (const float*)d_in[4];
    float* out = (float*)d_out;

    dim3 grid(B_SZ * NTB);   // 2048 blocks x 512 threads
    trc_conv_kernel<<<grid, 512, 0, stream>>>(x, conv_w, conv_b,
                                              leftout_w, leftout_b, out);
}

// Round 12
// 48.963 us; speedup vs baseline: 1.5283x; 1.5283x over previous
//
#include <hip/hip_runtime.h>

#define C_IN     7
#define D_MODEL  512
#define TAO      3
#define M_TAPS   5
#define KERNELS  73            // D_MODEL / C_IN
#define B_SZ     32
#define L_SZ     4096
#define TB       64            // t-positions per block
#define NTB      (L_SZ / TB)   // 64
#define ROWS     (TB + 17)     // 81 staged rows
#define SHIFT    3             // xs row r at index r+3 -> chunk fills 16B-aligned
#define RPAD     88
#define CHUNK    8             // rows per wave-local chunk
#define NCH      (TB / CHUNK)  // 8

__global__ __launch_bounds__(512, 6) void trc_conv_kernel(
    const float* __restrict__ x,          // [B, L, C_IN]
    const float* __restrict__ conv_w,     // [73, 6, 3]
    const float* __restrict__ conv_b,     // [73]
    const float* __restrict__ leftout_w,  // [1, 6, 3]
    const float* __restrict__ leftout_b,  // [1]
    float* __restrict__ out)              // [B, L, 512]
{
    __shared__ float xs[C_IN][RPAD];
    __shared__ __align__(16) float buf[8][2][CHUNK][64];  // per-wave dbuf out-tiles (32 KB)

    const int tid = threadIdx.x;
    const int wv  = tid >> 6;        // wave id 0..7 -> owns cols [64*wv, 64*wv+64)
    const int ln  = tid & 63;
    const int b   = blockIdx.x / NTB;
    const int tb  = blockIdx.x % NTB;
    const int t0  = tb * TB;

    // Stage x rows [t0-16, t0+TB] (circular), transposed [ch][row], +3 shift.
    const float* xb = x + (size_t)b * L_SZ * C_IN;
    for (int i = tid; i < ROWS * C_IN; i += 512) {
        int r = i / C_IN, c = i - r * C_IN;
        int g = t0 - 16 + r;
        if (g < 0)      g += L_SZ;
        if (g >= L_SZ)  g -= L_SZ;
        xs[c][r + SHIFT] = xb[(size_t)g * C_IN + c];
    }
    __syncthreads();   // the ONLY barrier

    // Column ownership: d = 64*wv + ln (== tid).
    const int d = tid;
    int ch;
    const float* wsrc;
    float bias;
    if (d < C_IN * KERNELS) {
        ch = d / KERNELS;
        int o = d - ch * KERNELS;
        wsrc = conv_w + o * 18;
        bias = conv_b[o];
    } else {
        ch = C_IN - 1;
        wsrc = leftout_w;
        bias = leftout_b[0];
    }
    const float* __restrict__ rowp = &xs[ch][SHIFT];   // rowp[r] = x row t0-16+r

    // FIR weights by row-offset j (0 = oldest = row t-16): k=j%3, m=(15+k-j)/3.
    float wreg[18];
    #pragma unroll
    for (int j = 0; j < 18; ++j) {
        int k = j % 3;
        int m = (15 + k - j) / 3;
        wreg[j] = wsrc[m * 3 + k];
    }

    const bool first = (tb == 0), last = (tb == NTB - 1);

    // Masked edge-row evaluation (wrap + validity).
    auto edge_eval = [&](int tl) -> float {
        float acc = bias;
        #pragma unroll
        for (int k = 0; k < 3; ++k) {
            int tt = t0 + tl + k - 1;
            if (tt < 0)      tt += L_SZ;
            if (tt >= L_SZ)  tt -= L_SZ;
            if (tt >= M_TAPS * TAO) {
                int lt = tl + 15 + k;
                #pragma unroll
                for (int m = 0; m < 6; ++m)
                    acc = fmaf(rowp[lt - 3 * m], wreg[15 + k - 3 * m], acc);
            }
        }
        return acc;
    };

    float* __restrict__ bufw = &buf[wv][0][0][0];        // wave-private
    const int lr = ln >> 4, lc = ln & 15;                // store lane mapping
    float4* base4 = (float4*)(out + ((size_t)b * L_SZ + t0) * D_MODEL + wv * 64);

    // Sliding window (static indices), chunk = 8 rows, b128 fills.
    float win[25];
    #pragma unroll
    for (int q = 0; q < 17; ++q) win[q] = rowp[q];

    float4 r0, r1;

    for (int c = 0; c < NCH; ++c) {
        float* __restrict__ bc = bufw + (c & 1) * (CHUNK * 64);

        // Fill rows 8c+17 .. 8c+24 : lds idx 8c+20 (16B aligned) -> 2x b128.
        {
            float4 f0 = *(const float4*)&rowp[8 * c + 17];
            float4 f1 = *(const float4*)&rowp[8 * c + 21];
            win[17] = f0.x; win[18] = f0.y; win[19] = f0.z; win[20] = f0.w;
            win[21] = f1.x; win[22] = f1.y; win[23] = f1.z; win[24] = f1.w;
        }

        #pragma unroll
        for (int i = 0; i < CHUNK; ++i) {
            float acc = bias;
            #pragma unroll
            for (int j = 0; j < 18; ++j)
                acc = fmaf(win[i + j], wreg[j], acc);
            bc[i * 64 + ln] = acc;                        // stride-1: conflict-free
        }
        #pragma unroll
        for (int q = 0; q < 17; ++q) win[q] = win[q + 8];

        // Cold edge fix-ups (block-uniform; 2/64 blocks only).
        if (first && c < 2) {
            for (int i = 0; i < CHUNK; ++i)
                bc[i * 64 + ln] = edge_eval(c * CHUNK + i);
        }
        if (last && c == NCH - 1) {
            bc[(CHUNK - 1) * 64 + ln] = edge_eval(TB - 1);
        }

        // Readback THIS chunk; store it next iteration (DS latency hides
        // under the next chunk's FMA block). DS is in-order per wave.
        const float4* bv = (const float4*)bc;
        float4 n0 = bv[ln];          // rows 0..3 of chunk
        float4 n1 = bv[ln + 64];     // rows 4..7
        __builtin_amdgcn_sched_barrier(0);

        if (c > 0) {
            base4[(size_t)((c - 1) * CHUNK + 0 + lr) * (D_MODEL / 4) + lc] = r0;
            base4[(size_t)((c - 1) * CHUNK + 4 + lr) * (D_MODEL / 4) + lc] = r1;
        }
        r0 = n0; r1 = n1;
    }
    base4[(size_t)((NCH - 1) * CHUNK + 0 + lr) * (D_MODEL / 4) + lc] = r0;
    base4[(size_t)((NCH - 1) * CHUNK + 4 + lr) * (D_MODEL / 4) + lc] = r1;
}

extern "C" void kernel_launch(void* const* d_in, const int* in_sizes, int n_in,
                              void* d_out, int out_size, void* d_ws, size_t ws_size,
                              hipStream_t stream) {
    const float* x          = (const float*)d_in[0];
    const float* conv_w     = (const float*)d_in[1];
    const float* conv_b     = (const float*)d_in[2];
    const float* leftout_w  = (const float*)d_in[3];
    const float* leftout_b  = (const float*)d_in[4];
    float* out = (float*)d_out;

    dim3 grid(B_SZ * NTB);   // 2048 blocks x 512 threads
    trc_conv_kernel<<<grid, 512, 0, stream>>>(x, conv_w, conv_b,
                                              leftout_w, leftout_b, out);
}